// Round 1
// baseline (77.546 us; speedup 1.0000x reference)
//
#include <hip/hip_runtime.h>

#define B_   8
#define OXD  30
#define OYD  30
#define OZD  14
#define NLOC (OXD*OYD*OZD)   // 12600
#define CIN  8
#define F_   16
#define T_   216             // 3*3*3*8
#define WPL  (T_*F_)         // 3456 weights per location

__global__ __launch_bounds__(128)
void lc3d_kernel(const float* __restrict__ in, const float* __restrict__ wgt,
                 const float* __restrict__ bias, float* __restrict__ out) {
    __shared__ float patch[B_ * T_];     // 1728 floats = 6.9 KB
    __shared__ float red[128 * 33];      // padded partials, 16.9 KB

    const int loc = blockIdx.x;
    const int ox  = loc / (OYD * OZD);
    const int rem = loc - ox * (OYD * OZD);
    const int oy  = rem / OZD;
    const int oz  = rem - oy * OZD;
    const int tid = threadIdx.x;

    // ---- stage input patches: 8 b x 9 (i,j) segments of 24 contiguous floats (k,c)
    for (int idx = tid; idx < B_ * 9 * 24; idx += 128) {
        int seg = idx / 24;            // 0..71
        int off = idx - seg * 24;      // k*8+c
        int b   = seg / 9;
        int ij  = seg - b * 9;
        int i   = ij / 3;
        int j   = ij - i * 3;
        int g   = (((b * 32 + ox + i) * 32 + (oy + j)) * 16 + oz) * 8 + off;
        patch[b * T_ + ij * 24 + off] = in[g];
    }
    __syncthreads();

    // ---- main: stream weights from global (coalesced float4), reuse 8x across batch
    const int fq = tid & 3;            // f quadrant (f = 4*fq .. 4*fq+3)
    const int tg = tid >> 2;           // 0..31 t-group
    const float* wloc = wgt + (size_t)loc * WPL;

    float acc[B_][4];
    #pragma unroll
    for (int b = 0; b < B_; ++b)
        #pragma unroll
        for (int i = 0; i < 4; ++i) acc[b][i] = 0.f;

    #pragma unroll
    for (int it = 0; it < 7; ++it) {
        int t = tg + 32 * it;
        if (t < T_) {
            const float4 w = *reinterpret_cast<const float4*>(wloc + t * F_ + fq * 4);
            #pragma unroll
            for (int b = 0; b < B_; ++b) {
                float p = patch[b * T_ + t];
                acc[b][0] += p * w.x;
                acc[b][1] += p * w.y;
                acc[b][2] += p * w.z;
                acc[b][3] += p * w.w;
            }
        }
    }

    // ---- write partials to LDS (stride 33 to avoid bank conflicts)
    #pragma unroll
    for (int b = 0; b < B_; ++b)
        #pragma unroll
        for (int i = 0; i < 4; ++i)
            red[tid * 33 + b * 4 + i] = acc[b][i];
    __syncthreads();

    // ---- final reduce over 32 t-groups: thread o -> output (b, f)
    {
        const int o   = tid;          // 0..127
        const int b   = o >> 4;       // 0..7
        const int f   = o & 15;
        const int fq2 = f >> 2;
        const int fi  = f & 3;
        float s = 0.f;
        #pragma unroll
        for (int g = 0; g < 32; ++g)
            s += red[(g * 4 + fq2) * 33 + b * 4 + fi];
        s += bias[loc * F_ + f];
        out[((size_t)b * NLOC + loc) * F_ + f] = s;
    }
}

extern "C" void kernel_launch(void* const* d_in, const int* in_sizes, int n_in,
                              void* d_out, int out_size, void* d_ws, size_t ws_size,
                              hipStream_t stream) {
    const float* in   = (const float*)d_in[0];
    const float* wgt  = (const float*)d_in[1];
    const float* bias = (const float*)d_in[2];
    float* out = (float*)d_out;
    lc3d_kernel<<<NLOC, 128, 0, stream>>>(in, wgt, bias, out);
}

// Round 2
// 37.052 us; speedup vs baseline: 2.0929x; 2.0929x over previous
//
#include <hip/hip_runtime.h>

#define B_   8
#define OXD  30
#define OYD  30
#define OZD  14
#define NLOC (OXD*OYD*OZD)   // 12600
#define CIN  8
#define F_   16
#define T_   216             // 3*3*3*8
#define WPL  (T_*F_)         // 3456 weights per location

__global__ __launch_bounds__(128)
void lc3d_kernel(const float* __restrict__ in, const float* __restrict__ wgt,
                 const float* __restrict__ bias, float* __restrict__ out) {
    // patch is dead once the main loop finishes -> overlay the reduction
    // scratch on top of it. LDS = 16.9 KB (was 24 KB) -> ~9 blocks/CU.
    __shared__ union {
        float patch[B_ * T_];     // 1728 floats (6.9 KB)
        float red[128 * 33];      // 4224 floats (16.9 KB)
    } sm;
    float4* patch4 = reinterpret_cast<float4*>(sm.patch);

    const int loc = blockIdx.x;
    const int ox  = loc / (OYD * OZD);
    const int rem = loc - ox * (OYD * OZD);
    const int oy  = rem / OZD;
    const int oz  = rem - oy * OZD;
    const int tid = threadIdx.x;

    const int fq = tid & 3;            // f quadrant (f = 4*fq .. 4*fq+3)
    const int tg = tid >> 2;           // 0..31 t-group
    const float* wloc = wgt + (size_t)loc * WPL;

    // prefetch bias for this thread's eventual output (b,f) = (tid>>4, tid&15)
    const float bi = bias[loc * F_ + (tid & 15)];

    // ---- issue ALL weight loads up front: latency hides under patch staging.
    // Per wave each iteration covers 1 KB contiguous -> fully coalesced.
    float4 w[7];
    #pragma unroll
    for (int it = 0; it < 6; ++it)
        w[it] = *reinterpret_cast<const float4*>(wloc + (tg + 32 * it) * F_ + fq * 4);
    w[6] = make_float4(0.f, 0.f, 0.f, 0.f);
    if (tg < 24)                       // 216 = 6*32 + 24
        w[6] = *reinterpret_cast<const float4*>(wloc + (tg + 192) * F_ + fq * 4);

    // ---- stage input patches as float4: 8b x 9(i,j) segments of 6 float4
    // (24 floats = k*8+c, float4-aligned since base is a multiple of 8 floats)
    const float4* in4 = reinterpret_cast<const float4*>(in);
    #pragma unroll
    for (int r = 0; r < 4; ++r) {
        int idx = tid + 128 * r;       // 0..431
        if (r < 3 || idx < 432) {
            int seg = idx / 6;         // 0..71 = b*9 + ij
            int off = idx - seg * 6;
            int b   = seg / 9;
            int ij  = seg - b * 9;
            int i   = ij / 3;
            int j   = ij - i * 3;
            int g4  = (((b * 32 + ox + i) * 32 + (oy + j)) * 16 + oz) * 2 + off;
            patch4[idx] = in4[g4];
        }
    }
    __syncthreads();

    // ---- main FMA loop: weights already in registers, 8x batch reuse each
    float acc[B_][4];
    #pragma unroll
    for (int b = 0; b < B_; ++b)
        #pragma unroll
        for (int i = 0; i < 4; ++i) acc[b][i] = 0.f;

    #pragma unroll
    for (int it = 0; it < 7; ++it) {
        const int t  = tg + 32 * it;
        const int tc = (t < T_) ? t : 0;   // clamp: w[6]=0 there, avoid 0*NaN
        const float4 ww = w[it];
        #pragma unroll
        for (int b = 0; b < B_; ++b) {
            const float p = sm.patch[b * T_ + tc];   // broadcast across fq lanes
            acc[b][0] += p * ww.x;
            acc[b][1] += p * ww.y;
            acc[b][2] += p * ww.z;
            acc[b][3] += p * ww.w;
        }
    }
    __syncthreads();   // all patch reads done before red overwrites the union

    // ---- write partials (stride 33 -> conflict-free)
    #pragma unroll
    for (int b = 0; b < B_; ++b)
        #pragma unroll
        for (int i = 0; i < 4; ++i)
            sm.red[tid * 33 + b * 4 + i] = acc[b][i];
    __syncthreads();

    // ---- final reduce over 32 t-groups: thread o -> output (b, f)
    {
        const int b   = tid >> 4;
        const int f   = tid & 15;
        const int fq2 = f >> 2;
        const int fi  = f & 3;
        float s = bi;
        #pragma unroll
        for (int g = 0; g < 32; ++g)
            s += sm.red[(g * 4 + fq2) * 33 + b * 4 + fi];
        out[((size_t)b * NLOC + loc) * F_ + f] = s;
    }
}

extern "C" void kernel_launch(void* const* d_in, const int* in_sizes, int n_in,
                              void* d_out, int out_size, void* d_ws, size_t ws_size,
                              hipStream_t stream) {
    const float* in   = (const float*)d_in[0];
    const float* wgt  = (const float*)d_in[1];
    const float* bias = (const float*)d_in[2];
    float* out = (float*)d_out;
    lc3d_kernel<<<NLOC, 128, 0, stream>>>(in, wgt, bias, out);
}

// Round 3
// 36.566 us; speedup vs baseline: 2.1207x; 1.0133x over previous
//
#include <hip/hip_runtime.h>

#define B_   8
#define OXD  30
#define OYD  30
#define OZD  14
#define NLOC (OXD*OYD*OZD)   // 12600
#define CIN  8
#define F_   16
#define T_   216             // 3*3*3*8
#define WPL  (T_*F_)         // 3456 weights per location

__global__ __launch_bounds__(128)
void lc3d_kernel(const float* __restrict__ in, const float* __restrict__ wgt,
                 const float* __restrict__ bias, float* __restrict__ out) {
    __shared__ float patch[B_ * T_];   // 1728 floats = 6.9 KB
    __shared__ float red[2 * 128];     // 2 waves x 128 partials = 1 KB
    float4* patch4 = reinterpret_cast<float4*>(patch);

    const int loc = blockIdx.x;
    const int ox  = loc / (OYD * OZD);
    const int rem = loc - ox * (OYD * OZD);
    const int oy  = rem / OZD;
    const int oz  = rem - oy * OZD;
    const int tid = threadIdx.x;

    const int fq = tid & 3;            // f quadrant (f = 4*fq .. 4*fq+3)
    const int tg = tid >> 2;           // 0..31 t-group
    const float* wloc = wgt + (size_t)loc * WPL;

    // bias for this thread's eventual output (b,f) = (tid>>4, tid&15)
    const float bi = bias[loc * F_ + (tid & 15)];

    // ---- issue ALL weight loads up front (1 KB contiguous per wave per it)
    float4 w[7];
    #pragma unroll
    for (int it = 0; it < 6; ++it)
        w[it] = *reinterpret_cast<const float4*>(wloc + (tg + 32 * it) * F_ + fq * 4);
    w[6] = make_float4(0.f, 0.f, 0.f, 0.f);
    if (tg < 24)                       // 216 = 6*32 + 24
        w[6] = *reinterpret_cast<const float4*>(wloc + (tg + 192) * F_ + fq * 4);

    // ---- stage input patches as float4 (weight latency hides under this)
    const float4* in4 = reinterpret_cast<const float4*>(in);
    #pragma unroll
    for (int r = 0; r < 4; ++r) {
        int idx = tid + 128 * r;       // 0..431
        if (r < 3 || idx < 432) {
            int seg = idx / 6;         // 0..71 = b*9 + ij
            int off = idx - seg * 6;
            int b   = seg / 9;
            int ij  = seg - b * 9;
            int i   = ij / 3;
            int j   = ij - i * 3;
            int g4  = (((b * 32 + ox + i) * 32 + (oy + j)) * 16 + oz) * 2 + off;
            patch4[idx] = in4[g4];
        }
    }
    __syncthreads();

    // ---- main FMA loop: a[b*4+fi] accumulators
    float a[32];
    #pragma unroll
    for (int e = 0; e < 32; ++e) a[e] = 0.f;

    #pragma unroll
    for (int it = 0; it < 7; ++it) {
        const int t  = tg + 32 * it;
        const int tc = (t < T_) ? t : 0;   // clamp: w[6]=0 there, avoid 0*NaN
        const float4 ww = w[it];
        #pragma unroll
        for (int b = 0; b < B_; ++b) {
            const float p = patch[b * T_ + tc];   // broadcast across fq lanes
            a[b * 4 + 0] += p * ww.x;
            a[b * 4 + 1] += p * ww.y;
            a[b * 4 + 2] += p * ww.z;
            a[b * 4 + 3] += p * ww.w;
        }
    }

    // ---- in-wave butterfly over the 16 in-wave t-groups (lane bits 2..5),
    // folding elements each step: 16+8+4+2 = 30 shuffles. Ends with 2
    // partials per lane at element index eg (derived from lane bits).
#define RSTEP(m, k)                                         \
    {                                                       \
        const bool hi = (tid & (m)) != 0;                   \
        _Pragma("unroll")                                   \
        for (int e = 0; e < (k); ++e) {                     \
            float v = hi ? a[e] : a[e + (k)];               \
            float r = __shfl_xor(v, (m), 64);               \
            a[e] = (hi ? a[e + (k)] : a[e]) + r;            \
        }                                                   \
    }
    RSTEP(4, 16)
    RSTEP(8, 8)
    RSTEP(16, 4)
    RSTEP(32, 2)
#undef RSTEP

    // element base this lane holds: eg and eg+1 (eg = b*4+fi layout)
    const int eg = ((tid & 4) << 2) | (tid & 8) | ((tid & 16) >> 2) | ((tid & 32) >> 4);
    const int wv = tid >> 6;
    red[wv * 128 + (eg + 0) * 4 + fq] = a[0];
    red[wv * 128 + (eg + 1) * 4 + fq] = a[1];
    __syncthreads();

    // ---- final: thread -> output (b, f); just 2 LDS reads (one per wave)
    {
        const int b   = tid >> 4;
        const int f   = tid & 15;
        const int fq2 = f >> 2;
        const int fi  = f & 3;
        const int e2  = (b * 4 + fi) * 4 + fq2;
        const float s = bi + red[e2] + red[128 + e2];
        out[((size_t)b * NLOC + loc) * F_ + f] = s;
    }
}

extern "C" void kernel_launch(void* const* d_in, const int* in_sizes, int n_in,
                              void* d_out, int out_size, void* d_ws, size_t ws_size,
                              hipStream_t stream) {
    const float* in   = (const float*)d_in[0];
    const float* wgt  = (const float*)d_in[1];
    const float* bias = (const float*)d_in[2];
    float* out = (float*)d_out;
    lc3d_kernel<<<NLOC, 128, 0, stream>>>(in, wgt, bias, out);
}